// Round 15
// baseline (194.854 us; speedup 1.0000x reference)
//
#include <hip/hip_runtime.h>
#include <type_traits>

#define DEVI __device__ __forceinline__

typedef unsigned short u16;
typedef unsigned int u32;
typedef float f32x4 __attribute__((ext_vector_type(4)));
typedef __bf16 bf16x8 __attribute__((ext_vector_type(8)));
typedef unsigned short u16x4 __attribute__((ext_vector_type(4)));
typedef unsigned short u16x8 __attribute__((ext_vector_type(8)));
typedef unsigned int u32x2 __attribute__((ext_vector_type(2)));

constexpr int BATCH = 2;
constexpr int T     = 2048;
constexpr int DIM   = 2048;
constexpr int NH    = 16;
constexpr int KVH   = 4;
constexpr int HD    = 128;
constexpr int NQKV  = DIM + 2 * KVH * HD;   // 3072 (q | k | v columns)
constexpr int ROWS  = BATCH * T;            // 4096
constexpr float SC2 = 0.08838834764831845f * 1.4426950408889634f; // (1/sqrt(HD))*log2(e)

DEVI u16 f2b(float f) {            // fp32 -> bf16 bits, round-nearest-even
  u32 u = __float_as_uint(f);
  return (u16)((u + 0x7fffu + ((u >> 16) & 1u)) >> 16);
}
DEVI float b2f(u16 u) { return __uint_as_float(((u32)u) << 16); }

DEVI u32 cvtpk(float lo, float hi) {   // 2xf32 -> packed bf16 pair
  u32 r;
  asm("v_cvt_pk_bf16_f32 %0, %1, %2" : "=v"(r) : "v"(lo), "v"(hi));
  return r;
}

DEVI f32x4 mfma16(bf16x8 a, bf16x8 b, f32x4 c) {
  return __builtin_amdgcn_mfma_f32_16x16x32_bf16(a, b, c, 0, 0, 0);
}
DEVI void gload16(const void* g, void* l) {  // async global->LDS, 16B/lane
  __builtin_amdgcn_global_load_lds((const __attribute__((address_space(1))) void*)g,
                                   (__attribute__((address_space(3))) void*)l, 16, 0, 0);
}

// ---------------- merged prep kernel ----------------
__global__ void cvt_all_kernel(const float* __restrict__ x,
                               const float* __restrict__ Wq, const float* __restrict__ Wk,
                               const float* __restrict__ Wv, const float* __restrict__ Wo,
                               const float* __restrict__ cosp, const float* __restrict__ sinp,
                               u16* __restrict__ xb, u16* __restrict__ wqkv,
                               u16* __restrict__ wout, float* __restrict__ cs)
{
  constexpr int S0 = ROWS * DIM / 4;   // x
  constexpr int S1 = DIM * DIM / 4;    // Wq
  constexpr int S2 = 512 * DIM / 4;    // Wk
  constexpr int S3 = 512 * DIM / 4;    // Wv
  constexpr int S4 = DIM * DIM / 4;    // Wo
  constexpr int S5 = T * HD / 4;       // cs
  int i = blockIdx.x * 256 + threadIdx.x;
  const float* src; u16* dst;
  if (i < S0) { src = x; dst = xb; }
  else if ((i -= S0) < S1) { src = Wq; dst = wqkv; }
  else if ((i -= S1) < S2) { src = Wk; dst = wqkv + DIM * DIM; }
  else if ((i -= S2) < S3) { src = Wv; dst = wqkv + (size_t)(DIM + 512) * DIM; }
  else if ((i -= S3) < S4) { src = Wo; dst = wout; }
  else if ((i -= S4) < S5) {
    float4 c = ((const float4*)cosp)[i];
    float4 s = ((const float4*)sinp)[i];
    float4 o = { c.x + s.x, c.y + s.y, c.z + s.z, c.w + s.w };
    ((float4*)cs)[i] = o;
    return;
  } else return;
  float4 v = ((const float4*)src)[i];
  u16x4 o = { f2b(v.x), f2b(v.y), f2b(v.z), f2b(v.w) };
  ((u16x4*)dst)[i] = o;
}

// ---------------- GEMM (R3-proven 128x128): C = A @ W^T (+bias) ----------------
template<bool BF16OUT, bool BIAS>
__global__ __launch_bounds__(256) void gemm_bt_kernel(
    const u16* __restrict__ A, const u16* __restrict__ W,
    void* __restrict__ Cout, const float* __restrict__ bias,
    int M, int N, int K)
{
  constexpr int BK = 64;
  __shared__ u16 sA[128 * BK];
  __shared__ u16 sB[128 * BK];
  const int nbx = N >> 7;
  const int bx = blockIdx.x % nbx;
  const int by = blockIdx.x / nbx;
  const int m0 = by << 7, n0 = bx << 7;
  const int tid = threadIdx.x;
  const int w = tid >> 6, lane = tid & 63;
  const int wr = w >> 1, wc = w & 1;
  const int lq = lane & 15, lg = lane >> 4;

  f32x4 acc[4][4] = {};

  int srow[4], scb[4];
#pragma unroll
  for (int c = 0; c < 4; ++c) {
    int off = (w * 4 + c) * 1024 + lane * 16;       // byte offset in 16KB tile
    srow[c] = off >> 7;                             // 128B per row (64 bf16)
    scb[c]  = (off & 127) ^ ((srow[c] & 7) << 4);   // pre-swizzled source col-byte
  }

  for (int kt = 0; kt < K; kt += BK) {
#pragma unroll
    for (int c = 0; c < 4; ++c) {
      u16* la = sA + (w * 4 + c) * 512;             // wave-uniform LDS dest
      u16* lb = sB + (w * 4 + c) * 512;
      gload16(A + (size_t)(m0 + srow[c]) * K + kt + (scb[c] >> 1), la);
      gload16(W + (size_t)(n0 + srow[c]) * K + kt + (scb[c] >> 1), lb);
    }
    __syncthreads();
#pragma unroll
    for (int ks = 0; ks < 2; ++ks) {
      bf16x8 af[4], bfr[4];
#pragma unroll
      for (int i = 0; i < 4; ++i) {
        int ra = wr * 64 + i * 16 + lq;
        int ca = (ks * 64 + lg * 16) ^ ((ra & 7) << 4);
        af[i] = *(const bf16x8*)((const char*)sA + ra * 128 + ca);
        int rb = wc * 64 + i * 16 + lq;
        int cb = (ks * 64 + lg * 16) ^ ((rb & 7) << 4);
        bfr[i] = *(const bf16x8*)((const char*)sB + rb * 128 + cb);
      }
#pragma unroll
      for (int i = 0; i < 4; ++i)
#pragma unroll
        for (int j = 0; j < 4; ++j)
          acc[i][j] = mfma16(af[i], bfr[j], acc[i][j]);
    }
    __syncthreads();
  }

  const int crow = m0 + wr * 64 + lg * 4;
  const int ccol = n0 + wc * 64 + lq;
#pragma unroll
  for (int j = 0; j < 4; ++j) {
    int col = ccol + j * 16;
    float bv = BIAS ? bias[col] : 0.0f;
#pragma unroll
    for (int i = 0; i < 4; ++i)
#pragma unroll
      for (int r = 0; r < 4; ++r) {
        size_t idx = (size_t)(crow + i * 16 + r) * N + col;
        float v = acc[i][j][r] + bv;
        if (BF16OUT) ((u16*)Cout)[idx] = f2b(v);
        else         ((float*)Cout)[idx] = v;
      }
  }
}

// ---------------- RoPE (K only; Q fused into attn) ----------------
__global__ void rope_k_kernel(const u16* __restrict__ Y, const float* __restrict__ cs,
                              u16* __restrict__ kr)
{
  int pid = blockIdx.x * 256 + threadIdx.x;
  int i  = pid & 63;                 // pair index (d = 2i)
  int hr = pid >> 6;
  int h  = hr & (KVH - 1);
  int r  = hr / KVH;                 // 0..ROWS-1
  int t  = r & (T - 1);
  int b  = r >> 11;
  u32 y = *(const u32*)(Y + (size_t)r * NQKV + DIM + h * HD + 2 * i);
  float y0 = b2f((u16)(y & 0xffffu));
  float y1 = b2f((u16)(y >> 16));
  const float* cp = cs + t * HD + 2 * i;
  u32 o = (u32)f2b(-y1 * cp[0]) | ((u32)f2b(y0 * cp[1]) << 16);
  *(u32*)(kr + (((size_t)(b * KVH + h) * T + t) * HD + 2 * i)) = o;
}

// V transpose via LDS tile: Vt[b][kh][d][t] = Y[b*T+t][2560 + kh*HD + d]
__global__ __launch_bounds__(256) void vt_kernel(const u16* __restrict__ Y, u16* __restrict__ vt)
{
  __shared__ u16 tile[64][136];            // 64 t-rows x 128 d (+8 pad)
  const int tid = threadIdx.x;
  const int tc = blockIdx.x & 31;          // 64-row t chunk
  const int kh = (blockIdx.x >> 5) & 3;
  const int b  = blockIdx.x >> 7;
  const u16* src = Y + (size_t)(b * T + tc * 64) * NQKV + (DIM + KVH * HD) + kh * HD;
#pragma unroll
  for (int pass = 0; pass < 4; ++pass) {
    int r = pass * 16 + (tid >> 4);
    int c = (tid & 15) * 8;
    *(u16x8*)&tile[r][c] = *(const u16x8*)(src + (size_t)r * NQKV + c);
  }
  __syncthreads();
  const int d = tid >> 1, th = tid & 1;
  u16* dst = vt + ((size_t)((b * KVH + kh) * HD + d) * T) + tc * 64 + th * 32;
#pragma unroll
  for (int j = 0; j < 4; ++j) {
    u16x8 v;
#pragma unroll
    for (int e = 0; e < 8; ++e) v[e] = tile[th * 32 + j * 8 + e][d];
    *(u16x8*)(dst + j * 8) = v;
  }
}

// ---------------- attention ---------------- (R14 phase structure, 4 waves x
// ONE 16-row q-group each; block = one 64-row q-chunk. Grid 1024 x 4 waves =
// 4096 resident waves = 4/SIMD (R9-R14 all ran 2/SIMD -- grid x waves/block
// never exceeded 2048; capacity without grid is not occupancy). LDS 37.9KB ->
// 4 blocks/CU. LPT dispatch: qc descending. Single-buffered K/V with the
// R14 two-barrier step. Fences in P roundtrip LOAD-BEARING (R11).)
__global__ __launch_bounds__(256, 4) void attn_kernel(
    const u16* __restrict__ Y, const float* __restrict__ cs,
    const u16* __restrict__ Kr, const u16* __restrict__ Vt,
    u16* __restrict__ Aout)
{
  __shared__ u16 ldsK[64 * 128];      // [s][d] rows 256B, swizzled (16 KB)
  __shared__ u16 ldsV[128 * 64];      // [d][s] rows 128B, swizzled (16 KB)
  __shared__ u16 ldsP[4][16 * 40];    // per-wave P relayout (5 KB)

  const int tid = threadIdx.x;
  const int w = tid >> 6, lane = tid & 63;
  const int lq = lane & 15, lg = lane >> 4;

  // mapping: x = XCD / (b,kh) group; j -> (h_sub, qc descending = LPT)
  const int x  = blockIdx.x & 7;
  const int j  = blockIdx.x >> 3;           // 0..127
  const int bh = (x >> 2) * 16 + (x & 3) * 4 + (j & 3);
  const int qc = 31 - (j >> 2);             // 31..0, longest first
  const int b = bh >> 4, h = bh & 15, kh = h >> 2;
  const int rowQ = qc * 64 + w * 16;
  const int nst = qc + 1;                   // tiles of 64 s

  // Q fragments: load from yqkv, apply rope in-register (pairs adjacent), *SC2
  bf16x8 qf[4];
  {
    const u16* yp = Y + ((size_t)(b * T + rowQ + lq)) * NQKV + h * HD + lg * 8;
    const float* cp = cs + (rowQ + lq) * HD + lg * 8;
#pragma unroll
    for (int ds = 0; ds < 4; ++ds) {
      u16x8 y = *(const u16x8*)(yp + ds * 32);
      float4 c0 = *(const float4*)(cp + ds * 32);
      float4 c1 = *(const float4*)(cp + ds * 32 + 4);
      u16x8 o;
      o[0] = f2b(-b2f(y[1]) * c0.x * SC2); o[1] = f2b(b2f(y[0]) * c0.y * SC2);
      o[2] = f2b(-b2f(y[3]) * c0.z * SC2); o[3] = f2b(b2f(y[2]) * c0.w * SC2);
      o[4] = f2b(-b2f(y[5]) * c1.x * SC2); o[5] = f2b(b2f(y[4]) * c1.y * SC2);
      o[6] = f2b(-b2f(y[7]) * c1.z * SC2); o[7] = f2b(b2f(y[6]) * c1.w * SC2);
      qf[ds] = *(bf16x8*)&o;
    }
  }

  const u16* Kg = Kr + (size_t)(b * KVH + kh) * T * HD;
  const u16* Vg = Vt + (size_t)(b * KVH + kh) * HD * T;

  int kgo[4], klb[4], vgo[4], vlb[4];
  {
    const int vr = lane >> 3, vc = lane & 7;
#pragma unroll
    for (int i = 0; i < 4; ++i) {
      int krow = w * 16 + i * 4 + lg;
      kgo[i] = krow * HD + (((lq * 16) ^ ((krow & 7) << 4)) >> 1);
      klb[i] = (w * 16 + i * 4) * 128;
      int vrow = w * 32 + i * 8 + vr;
      vgo[i] = vrow * T + (((vc * 16) ^ ((vr & 7) << 4)) >> 1);
      vlb[i] = (w * 32 + i * 8) * 64;
    }
  }

  f32x4 accO[8] = {};
  float lsum = 0.f;

  // prologue: stage K[0]
#pragma unroll
  for (int i = 0; i < 4; ++i) gload16(Kg + kgo[i], &ldsK[klb[i]]);
  __syncthreads();

  for (int t = 0; t < nst; ++t) {
    const int s0 = t << 6;

    // issue V[t] staging (lands by the mid __syncthreads)
    {
      const u16* Vts = Vg + t * 64;
#pragma unroll
      for (int i = 0; i < 4; ++i) gload16(Vts + vgo[i], &ldsV[vlb[i]]);
    }

    // ---- QK + softmax (reads ldsK = K[t]) ----
    float pp[16];
    {
      f32x4 aS[4] = {};
#pragma unroll
      for (int si = 0; si < 4; ++si)
#pragma unroll
        for (int ds = 0; ds < 4; ++ds) {
          const u16* kp = ldsK + (si * 16 + lq) * 128 +
                          (((ds * 64 + lg * 16) ^ ((lq & 7) << 4)) >> 1);
          bf16x8 kf = *(const bf16x8*)kp;
          aS[si] = mfma16(kf, qf[ds], aS[si]);
        }
      const int qidx = rowQ + lq;
      if (t == qc) {          // diagonal tile: causal mask
#pragma unroll
        for (int si = 0; si < 4; ++si)
#pragma unroll
          for (int r = 0; r < 4; ++r) {
            int sidx = s0 + si * 16 + lg * 4 + r;
            pp[si * 4 + r] = (sidx <= qidx) ? __builtin_amdgcn_exp2f(aS[si][r]) : 0.0f;
          }
      } else {
#pragma unroll
        for (int si = 0; si < 4; ++si)
#pragma unroll
          for (int r = 0; r < 4; ++r)
            pp[si * 4 + r] = __builtin_amdgcn_exp2f(aS[si][r]);
      }
      float ps = 0.f;
#pragma unroll
      for (int i2 = 0; i2 < 16; ++i2) ps += pp[i2];
      lsum += ps;
    }

    // mid barrier: V[t] landed (vmcnt drain) + all waves' K reads complete
    __syncthreads();

    // issue K[t+1] staging (ldsK free; lands by the end __syncthreads)
    if (t + 1 < nst) {
      const u16* Kt = Kg + (size_t)(t + 1) * 64 * HD;
#pragma unroll
      for (int i = 0; i < 4; ++i) gload16(Kt + kgo[i], &ldsK[klb[i]]);
    }

    // ---- P roundtrip + PV (reads ldsV = V[t]) ----
#pragma unroll
    for (int ks = 0; ks < 2; ++ks) {
      {
        u16* pw = &ldsP[w][lq * 40];
        u32x2 wa = { cvtpk(pp[8 * ks + 0], pp[8 * ks + 1]),
                     cvtpk(pp[8 * ks + 2], pp[8 * ks + 3]) };
        u32x2 wb = { cvtpk(pp[8 * ks + 4], pp[8 * ks + 5]),
                     cvtpk(pp[8 * ks + 6], pp[8 * ks + 7]) };
        *(u32x2*)(pw + lg * 4)      = wa;
        *(u32x2*)(pw + 16 + lg * 4) = wb;
      }
      asm volatile("" ::: "memory");   // LOAD-BEARING: cross-lane RAW (R11)
      bf16x8 pf = *(const bf16x8*)(&ldsP[w][lq * 40] + lg * 8);
      asm volatile("" ::: "memory");   // WAR fence for next ks iteration
#pragma unroll
      for (int db = 0; db < 8; ++db) {
        const u16* vp = ldsV + (db * 16 + lq) * 64 +
                        (((ks * 64 + lg * 16) ^ ((lq & 7) << 4)) >> 1);
        bf16x8 vf = *(const bf16x8*)vp;
        accO[db] = mfma16(vf, pf, accO[db]);
      }
    }

    // end barrier: K[t+1] landed + all waves' V reads complete
    __syncthreads();
  }

  // epilogue: deferred lsum reduce; lane holds O[q = rowQ+lq][d = db*16+lg*4+r]
  {
    float l = lsum;
    l += __shfl_xor(l, 16);
    l += __shfl_xor(l, 32);
    float inv = 1.0f / l;
    u16* Ab = Aout + ((size_t)b * T + rowQ + lq) * DIM + h * HD;
#pragma unroll
    for (int db = 0; db < 8; ++db) {
      u32x2 st = { cvtpk(accO[db][0] * inv, accO[db][1] * inv),
                   cvtpk(accO[db][2] * inv, accO[db][3] * inv) };
      *(u32x2*)(Ab + db * 16 + lg * 4) = st;
    }
  }
}

// ---------------- launch ----------------
extern "C" void kernel_launch(void* const* d_in, const int* in_sizes, int n_in,
                              void* d_out, int out_size, void* d_ws, size_t ws_size,
                              hipStream_t stream) {
  const float* x    = (const float*)d_in[0];
  const float* cosp = (const float*)d_in[1];
  const float* sinp = (const float*)d_in[2];
  // d_in[3] = mask (causal, computed analytically)
  const float* Wq   = (const float*)d_in[4];
  const float* Wk   = (const float*)d_in[5];
  const float* Wv   = (const float*)d_in[6];
  const float* Wo   = (const float*)d_in[7];
  const float* bo   = (const float*)d_in[8];

  char* ws = (char*)d_ws;
  u16*   xb   = (u16*)(ws + 0);          // 16 MB  (ROWS*DIM bf16)   [reused as attn out]
  u16*   wqkv = (u16*)(ws + 16777216);   // 12 MB  (NQKV*DIM bf16)
  u16*   wout = (u16*)(ws + 29360128);   // 8 MB   (DIM*DIM bf16)
  float* cs   = (float*)(ws + 37748736); // 1 MB   (T*HD fp32)
  u16*   yqkv = (u16*)(ws + 38797312);   // 24 MB  (ROWS*NQKV bf16; q-cols read by attn)
  u16*   kr   = (u16*)(ws + 63963136);   // 4 MB
  u16*   vt   = (u16*)(ws + 68157440);   // 4 MB   (total 72,351,744 B)
  u16* aout = xb;   // attn output overwrites xb (xb consumed by GEMM1 before attn)

  constexpr int CVT_TOTAL = ROWS * DIM / 4 + DIM * DIM / 4 + 512 * DIM / 4 * 2
                          + DIM * DIM / 4 + T * HD / 4;
  cvt_all_kernel<<<(CVT_TOTAL + 255) / 256, 256, 0, stream>>>(
      x, Wq, Wk, Wv, Wo, cosp, sinp, xb, wqkv, wout, cs);

  gemm_bt_kernel<true, false><<<(ROWS / 128) * (NQKV / 128), 256, 0, stream>>>(
      xb, wqkv, yqkv, nullptr, ROWS, NQKV, DIM);

  rope_k_kernel<<<ROWS * KVH * 64 / 256, 256, 0, stream>>>(yqkv, cs, kr);
  vt_kernel<<<BATCH * KVH * (T / 64), 256, 0, stream>>>(yqkv, vt);

  attn_kernel<<<BATCH * NH * 32, 256, 0, stream>>>(yqkv, cs, kr, vt, aout);

  gemm_bt_kernel<false, true><<<(ROWS / 128) * (DIM / 128), 256, 0, stream>>>(
      aout, wout, d_out, bo, ROWS, DIM, DIM);
}

// Round 16
// 187.847 us; speedup vs baseline: 1.0373x; 1.0373x over previous
//
#include <hip/hip_runtime.h>
#include <type_traits>

#define DEVI __device__ __forceinline__

typedef unsigned short u16;
typedef unsigned int u32;
typedef float f32x4 __attribute__((ext_vector_type(4)));
typedef __bf16 bf16x8 __attribute__((ext_vector_type(8)));
typedef unsigned short u16x4 __attribute__((ext_vector_type(4)));
typedef unsigned short u16x8 __attribute__((ext_vector_type(8)));
typedef unsigned int u32x2 __attribute__((ext_vector_type(2)));

constexpr int BATCH = 2;
constexpr int T     = 2048;
constexpr int DIM   = 2048;
constexpr int NH    = 16;
constexpr int KVH   = 4;
constexpr int HD    = 128;
constexpr int NQKV  = DIM + 2 * KVH * HD;   // 3072 (q | k | v columns)
constexpr int ROWS  = BATCH * T;            // 4096
constexpr float SC2 = 0.08838834764831845f * 1.4426950408889634f; // (1/sqrt(HD))*log2(e)

DEVI u16 f2b(float f) {            // fp32 -> bf16 bits, round-nearest-even
  u32 u = __float_as_uint(f);
  return (u16)((u + 0x7fffu + ((u >> 16) & 1u)) >> 16);
}
DEVI float b2f(u16 u) { return __uint_as_float(((u32)u) << 16); }

DEVI u32 cvtpk(float lo, float hi) {   // 2xf32 -> packed bf16 pair
  u32 r;
  asm("v_cvt_pk_bf16_f32 %0, %1, %2" : "=v"(r) : "v"(lo), "v"(hi));
  return r;
}

DEVI f32x4 mfma16(bf16x8 a, bf16x8 b, f32x4 c) {
  return __builtin_amdgcn_mfma_f32_16x16x32_bf16(a, b, c, 0, 0, 0);
}
DEVI void gload16(const void* g, void* l) {  // async global->LDS, 16B/lane
  __builtin_amdgcn_global_load_lds((const __attribute__((address_space(1))) void*)g,
                                   (__attribute__((address_space(3))) void*)l, 16, 0, 0);
}

// ---------------- merged prep kernel ----------------
__global__ void cvt_all_kernel(const float* __restrict__ x,
                               const float* __restrict__ Wq, const float* __restrict__ Wk,
                               const float* __restrict__ Wv, const float* __restrict__ Wo,
                               const float* __restrict__ cosp, const float* __restrict__ sinp,
                               u16* __restrict__ xb, u16* __restrict__ wqkv,
                               u16* __restrict__ wout, float* __restrict__ cs)
{
  constexpr int S0 = ROWS * DIM / 4;   // x
  constexpr int S1 = DIM * DIM / 4;    // Wq
  constexpr int S2 = 512 * DIM / 4;    // Wk
  constexpr int S3 = 512 * DIM / 4;    // Wv
  constexpr int S4 = DIM * DIM / 4;    // Wo
  constexpr int S5 = T * HD / 4;       // cs
  int i = blockIdx.x * 256 + threadIdx.x;
  const float* src; u16* dst;
  if (i < S0) { src = x; dst = xb; }
  else if ((i -= S0) < S1) { src = Wq; dst = wqkv; }
  else if ((i -= S1) < S2) { src = Wk; dst = wqkv + DIM * DIM; }
  else if ((i -= S2) < S3) { src = Wv; dst = wqkv + (size_t)(DIM + 512) * DIM; }
  else if ((i -= S3) < S4) { src = Wo; dst = wout; }
  else if ((i -= S4) < S5) {
    float4 c = ((const float4*)cosp)[i];
    float4 s = ((const float4*)sinp)[i];
    float4 o = { c.x + s.x, c.y + s.y, c.z + s.z, c.w + s.w };
    ((float4*)cs)[i] = o;
    return;
  } else return;
  float4 v = ((const float4*)src)[i];
  u16x4 o = { f2b(v.x), f2b(v.y), f2b(v.z), f2b(v.w) };
  ((u16x4*)dst)[i] = o;
}

// ---------------- GEMM (R3-proven 128x128): C = A @ W^T (+bias) ----------------
template<bool BF16OUT, bool BIAS>
__global__ __launch_bounds__(256) void gemm_bt_kernel(
    const u16* __restrict__ A, const u16* __restrict__ W,
    void* __restrict__ Cout, const float* __restrict__ bias,
    int M, int N, int K)
{
  constexpr int BK = 64;
  __shared__ u16 sA[128 * BK];
  __shared__ u16 sB[128 * BK];
  const int nbx = N >> 7;
  const int bx = blockIdx.x % nbx;
  const int by = blockIdx.x / nbx;
  const int m0 = by << 7, n0 = bx << 7;
  const int tid = threadIdx.x;
  const int w = tid >> 6, lane = tid & 63;
  const int wr = w >> 1, wc = w & 1;
  const int lq = lane & 15, lg = lane >> 4;

  f32x4 acc[4][4] = {};

  int srow[4], scb[4];
#pragma unroll
  for (int c = 0; c < 4; ++c) {
    int off = (w * 4 + c) * 1024 + lane * 16;       // byte offset in 16KB tile
    srow[c] = off >> 7;                             // 128B per row (64 bf16)
    scb[c]  = (off & 127) ^ ((srow[c] & 7) << 4);   // pre-swizzled source col-byte
  }

  for (int kt = 0; kt < K; kt += BK) {
#pragma unroll
    for (int c = 0; c < 4; ++c) {
      u16* la = sA + (w * 4 + c) * 512;             // wave-uniform LDS dest
      u16* lb = sB + (w * 4 + c) * 512;
      gload16(A + (size_t)(m0 + srow[c]) * K + kt + (scb[c] >> 1), la);
      gload16(W + (size_t)(n0 + srow[c]) * K + kt + (scb[c] >> 1), lb);
    }
    __syncthreads();
#pragma unroll
    for (int ks = 0; ks < 2; ++ks) {
      bf16x8 af[4], bfr[4];
#pragma unroll
      for (int i = 0; i < 4; ++i) {
        int ra = wr * 64 + i * 16 + lq;
        int ca = (ks * 64 + lg * 16) ^ ((ra & 7) << 4);
        af[i] = *(const bf16x8*)((const char*)sA + ra * 128 + ca);
        int rb = wc * 64 + i * 16 + lq;
        int cb = (ks * 64 + lg * 16) ^ ((rb & 7) << 4);
        bfr[i] = *(const bf16x8*)((const char*)sB + rb * 128 + cb);
      }
#pragma unroll
      for (int i = 0; i < 4; ++i)
#pragma unroll
        for (int j = 0; j < 4; ++j)
          acc[i][j] = mfma16(af[i], bfr[j], acc[i][j]);
    }
    __syncthreads();
  }

  const int crow = m0 + wr * 64 + lg * 4;
  const int ccol = n0 + wc * 64 + lq;
#pragma unroll
  for (int j = 0; j < 4; ++j) {
    int col = ccol + j * 16;
    float bv = BIAS ? bias[col] : 0.0f;
#pragma unroll
    for (int i = 0; i < 4; ++i)
#pragma unroll
      for (int r = 0; r < 4; ++r) {
        size_t idx = (size_t)(crow + i * 16 + r) * N + col;
        float v = acc[i][j][r] + bv;
        if (BF16OUT) ((u16*)Cout)[idx] = f2b(v);
        else         ((float*)Cout)[idx] = v;
      }
  }
}

// ---------------- RoPE (K only; Q fused into attn) ----------------
__global__ void rope_k_kernel(const u16* __restrict__ Y, const float* __restrict__ cs,
                              u16* __restrict__ kr)
{
  int pid = blockIdx.x * 256 + threadIdx.x;
  int i  = pid & 63;                 // pair index (d = 2i)
  int hr = pid >> 6;
  int h  = hr & (KVH - 1);
  int r  = hr / KVH;                 // 0..ROWS-1
  int t  = r & (T - 1);
  int b  = r >> 11;
  u32 y = *(const u32*)(Y + (size_t)r * NQKV + DIM + h * HD + 2 * i);
  float y0 = b2f((u16)(y & 0xffffu));
  float y1 = b2f((u16)(y >> 16));
  const float* cp = cs + t * HD + 2 * i;
  u32 o = (u32)f2b(-y1 * cp[0]) | ((u32)f2b(y0 * cp[1]) << 16);
  *(u32*)(kr + (((size_t)(b * KVH + h) * T + t) * HD + 2 * i)) = o;
}

// V transpose via LDS tile: Vt[b][kh][d][t] = Y[b*T+t][2560 + kh*HD + d]
__global__ __launch_bounds__(256) void vt_kernel(const u16* __restrict__ Y, u16* __restrict__ vt)
{
  __shared__ u16 tile[64][136];            // 64 t-rows x 128 d (+8 pad)
  const int tid = threadIdx.x;
  const int tc = blockIdx.x & 31;          // 64-row t chunk
  const int kh = (blockIdx.x >> 5) & 3;
  const int b  = blockIdx.x >> 7;
  const u16* src = Y + (size_t)(b * T + tc * 64) * NQKV + (DIM + KVH * HD) + kh * HD;
#pragma unroll
  for (int pass = 0; pass < 4; ++pass) {
    int r = pass * 16 + (tid >> 4);
    int c = (tid & 15) * 8;
    *(u16x8*)&tile[r][c] = *(const u16x8*)(src + (size_t)r * NQKV + c);
  }
  __syncthreads();
  const int d = tid >> 1, th = tid & 1;
  u16* dst = vt + ((size_t)((b * KVH + kh) * HD + d) * T) + tc * 64 + th * 32;
#pragma unroll
  for (int j = 0; j < 4; ++j) {
    u16x8 v;
#pragma unroll
    for (int e = 0; e < 8; ++e) v[e] = tile[th * 32 + j * 8 + e][d];
    *(u16x8*)(dst + j * 8) = v;
  }
}

// ---------------- attention ---------------- (R10 body EXACT (best measured:
// 65.7us, setprio, fences, two-round complementary mapping, dbuf K/V) with ONE
// change: T4 counted-vmcnt sync replaces __syncthreads. R15 diagnosed ~2.4K
// cyc/step stall: __syncthreads = s_waitcnt vmcnt(0)+s_barrier DRAINS the
// just-issued prefetch every step. New step: compute(buf c) -> barrier (reads
// done) -> issue t+2 into buf c -> vmcnt(8) (t+1 landed; t+2 stays in flight)
// -> barrier. Per-wave vmcnt becomes collective via the following barrier
// (m201 pattern). nst>=17 always, so the 2-deep prologue is always valid.)
__global__ __launch_bounds__(256, 2) void attn_kernel(
    const u16* __restrict__ Y, const float* __restrict__ cs,
    const u16* __restrict__ Kr, const u16* __restrict__ Vt,
    u16* __restrict__ Aout)
{
  __shared__ u16 ldsK[2][64 * 128];   // [s][d] rows 256B, swizzled
  __shared__ u16 ldsV[2][128 * 64];   // [d][s] rows 128B, swizzled
  __shared__ u16 ldsP[4][32 * 40];    // per-wave P relayout

  const int tid = threadIdx.x;
  const int w = tid >> 6, lane = tid & 63;
  const int lq = lane & 15, lg = lane >> 4;

  // two-round complementary mapping (R10)
  const int s  = blockIdx.x & 255;          // slot within round
  const int r0 = blockIdx.x >> 8;           // round 0/1
  const int x  = s & 7;                     // XCD / (b,kh) group
  const int j  = s >> 3;                    // 0..31
  const int bh = (x >> 2) * 16 + (x & 3) * 4 + (j & 3);
  const int p  = r0 ? (8 + (j >> 2)) : (j >> 2);
  const int b = bh >> 4, h = bh & 15, kh = h >> 2;
  const int qcA = p, qcB = 31 - p;
  const int rowA = qcA * 64 + w * 16;
  const int rowB = qcB * 64 + w * 16;
  const int nst = qcB + 1;                   // tiles of 64 s; nst >= 17

  // Q fragments: load from yqkv, apply rope in-register (pairs adjacent), *SC2
  bf16x8 qf[2][4];
#pragma unroll
  for (int qg = 0; qg < 2; ++qg) {
    const int rowX = qg ? rowB : rowA;
    const u16* yp = Y + ((size_t)(b * T + rowX + lq)) * NQKV + h * HD + lg * 8;
    const float* cp = cs + (rowX + lq) * HD + lg * 8;
#pragma unroll
    for (int ds = 0; ds < 4; ++ds) {
      u16x8 y = *(const u16x8*)(yp + ds * 32);
      float4 c0 = *(const float4*)(cp + ds * 32);
      float4 c1 = *(const float4*)(cp + ds * 32 + 4);
      u16x8 o;
      o[0] = f2b(-b2f(y[1]) * c0.x * SC2); o[1] = f2b(b2f(y[0]) * c0.y * SC2);
      o[2] = f2b(-b2f(y[3]) * c0.z * SC2); o[3] = f2b(b2f(y[2]) * c0.w * SC2);
      o[4] = f2b(-b2f(y[5]) * c1.x * SC2); o[5] = f2b(b2f(y[4]) * c1.y * SC2);
      o[6] = f2b(-b2f(y[7]) * c1.z * SC2); o[7] = f2b(b2f(y[6]) * c1.w * SC2);
      qf[qg][ds] = *(bf16x8*)&o;
    }
  }

  const u16* Kg = Kr + (size_t)(b * KVH + kh) * T * HD;
  const u16* Vg = Vt + (size_t)(b * KVH + kh) * HD * T;

  int kgo[4], klb[4], vgo[4], vlb[4];
  {
    const int vr = lane >> 3, vc = lane & 7;
#pragma unroll
    for (int i = 0; i < 4; ++i) {
      int krow = w * 16 + i * 4 + lg;
      kgo[i] = krow * HD + (((lq * 16) ^ ((krow & 7) << 4)) >> 1);
      klb[i] = (w * 16 + i * 4) * 128;
      int vrow = w * 32 + i * 8 + vr;
      vgo[i] = vrow * T + (((vc * 16) ^ ((vr & 7) << 4)) >> 1);
      vlb[i] = (w * 32 + i * 8) * 64;
    }
  }

  f32x4 accO[2][8] = {};
  float lsum[2] = { 0.f, 0.f };

  // prologue: stage tile 0 -> buf0, tile 1 -> buf1 (nst >= 17 guarantees both)
#pragma unroll
  for (int i = 0; i < 4; ++i) {
    gload16(Kg + kgo[i], &ldsK[0][klb[i]]);
    gload16(Vg + vgo[i], &ldsV[0][vlb[i]]);
  }
  {
    const u16* Kt  = Kg + (size_t)64 * HD;
    const u16* Vts = Vg + 64;
#pragma unroll
    for (int i = 0; i < 4; ++i) {
      gload16(Kt + kgo[i],  &ldsK[1][klb[i]]);
      gload16(Vts + vgo[i], &ldsV[1][vlb[i]]);
    }
  }
  asm volatile("s_waitcnt vmcnt(8)" ::: "memory");   // tile 0 landed
  __builtin_amdgcn_s_barrier();
  asm volatile("" ::: "memory");

  int cur = 0;
  for (int t = 0; t < nst; ++t) {
    const int s0 = t << 6;
    const u16* Kb = ldsK[cur];
    const u16* Vb = ldsV[cur];

    auto softmax_qg = [&](f32x4 (&s4)[4], int qidx, bool diag, float& ls,
                          float (&pp)[16]) {
      if (diag) {
#pragma unroll
        for (int si = 0; si < 4; ++si)
#pragma unroll
          for (int r = 0; r < 4; ++r) {
            int sidx = s0 + si * 16 + lg * 4 + r;
            pp[si * 4 + r] = (sidx <= qidx) ? __builtin_amdgcn_exp2f(s4[si][r]) : 0.0f;
          }
      } else {
#pragma unroll
        for (int si = 0; si < 4; ++si)
#pragma unroll
          for (int r = 0; r < 4; ++r)
            pp[si * 4 + r] = __builtin_amdgcn_exp2f(s4[si][r]);
      }
      float ps = 0.f;
#pragma unroll
      for (int i2 = 0; i2 < 16; ++i2) ps += pp[i2];
      ls += ps;
    };

    auto tile_body = [&](auto hasA_c) {
      constexpr bool HASA = decltype(hasA_c)::value;
      f32x4 aS[2][4] = {};
      __builtin_amdgcn_s_setprio(1);
#pragma unroll
      for (int si = 0; si < 4; ++si)
#pragma unroll
        for (int ds = 0; ds < 4; ++ds) {
          const u16* kp = Kb + (si * 16 + lq) * 128 +
                          (((ds * 64 + lg * 16) ^ ((lq & 7) << 4)) >> 1);
          bf16x8 kf = *(const bf16x8*)kp;
          if constexpr (HASA) aS[0][si] = mfma16(kf, qf[0][ds], aS[0][si]);
          aS[1][si] = mfma16(kf, qf[1][ds], aS[1][si]);
        }
      __builtin_amdgcn_s_setprio(0);

      float pp[2][16];
      if constexpr (HASA)
        softmax_qg(aS[0], rowA + lq, t == qcA, lsum[0], pp[0]);
      softmax_qg(aS[1], rowB + lq, t == qcB, lsum[1], pp[1]);

#pragma unroll
      for (int ks = 0; ks < 2; ++ks) {
        if constexpr (HASA) {
          u16* pw = &ldsP[w][lq * 40];
          u32x2 wa = { cvtpk(pp[0][8 * ks + 0], pp[0][8 * ks + 1]),
                       cvtpk(pp[0][8 * ks + 2], pp[0][8 * ks + 3]) };
          u32x2 wb = { cvtpk(pp[0][8 * ks + 4], pp[0][8 * ks + 5]),
                       cvtpk(pp[0][8 * ks + 6], pp[0][8 * ks + 7]) };
          *(u32x2*)(pw + lg * 4)      = wa;
          *(u32x2*)(pw + 16 + lg * 4) = wb;
        }
        {
          u16* pw = &ldsP[w][(16 + lq) * 40];
          u32x2 wa = { cvtpk(pp[1][8 * ks + 0], pp[1][8 * ks + 1]),
                       cvtpk(pp[1][8 * ks + 2], pp[1][8 * ks + 3]) };
          u32x2 wb = { cvtpk(pp[1][8 * ks + 4], pp[1][8 * ks + 5]),
                       cvtpk(pp[1][8 * ks + 6], pp[1][8 * ks + 7]) };
          *(u32x2*)(pw + lg * 4)      = wa;
          *(u32x2*)(pw + 16 + lg * 4) = wb;
        }
        asm volatile("" ::: "memory");   // LOAD-BEARING: cross-lane RAW (R11)
        bf16x8 pf0, pf1;
        if constexpr (HASA) pf0 = *(const bf16x8*)(&ldsP[w][lq * 40] + lg * 8);
        pf1 = *(const bf16x8*)(&ldsP[w][(16 + lq) * 40] + lg * 8);
        asm volatile("" ::: "memory");   // WAR fence for next ks iteration
        __builtin_amdgcn_s_setprio(1);
#pragma unroll
        for (int db = 0; db < 8; ++db) {
          const u16* vp = Vb + (db * 16 + lq) * 64 +
                          (((ks * 64 + lg * 16) ^ ((lq & 7) << 4)) >> 1);
          bf16x8 vf = *(const bf16x8*)vp;
          if constexpr (HASA) accO[0][db] = mfma16(vf, pf0, accO[0][db]);
          accO[1][db] = mfma16(vf, pf1, accO[1][db]);
        }
        __builtin_amdgcn_s_setprio(0);
      }
    };

    if (t <= qcA) tile_body(std::integral_constant<bool, true>{});
    else          tile_body(std::integral_constant<bool, false>{});

    // ---- T4 sync: barrier A (reads of buf cur done) -> issue t+2 into buf
    // cur -> counted vmcnt (t+1 landed, t+2 in flight) -> barrier B ----
    asm volatile("" ::: "memory");
    __builtin_amdgcn_s_barrier();            // A: all waves done reading buf cur
    asm volatile("" ::: "memory");
    if (t + 2 < nst) {
      const u16* Kt  = Kg + (size_t)(t + 2) * 64 * HD;
      const u16* Vts = Vg + (t + 2) * 64;
#pragma unroll
      for (int i = 0; i < 4; ++i) {
        gload16(Kt + kgo[i],  &ldsK[cur][klb[i]]);
        gload16(Vts + vgo[i], &ldsV[cur][vlb[i]]);
      }
      asm volatile("s_waitcnt vmcnt(8)" ::: "memory");  // t+1's 8 landed
    } else if (t + 1 < nst) {
      asm volatile("s_waitcnt vmcnt(0)" ::: "memory");  // tail: drain t+1
    }
    __builtin_amdgcn_s_barrier();            // B: buf cur^1 ready for all waves
    asm volatile("" ::: "memory");
    cur ^= 1;
  }

  // epilogue: deferred lsum reduce; lane holds O[q = rowX+lq][d = db*16+lg*4+r]
#pragma unroll
  for (int qg = 0; qg < 2; ++qg) {
    const int rowX = qg ? rowB : rowA;
    float l = qg ? lsum[1] : lsum[0];
    l += __shfl_xor(l, 16);
    l += __shfl_xor(l, 32);
    float inv = 1.0f / l;
    u16* Ab = Aout + ((size_t)b * T + rowX + lq) * DIM + h * HD;
#pragma unroll
    for (int db = 0; db < 8; ++db) {
      f32x4 a = qg ? accO[1][db] : accO[0][db];
      u32x2 st = { cvtpk(a[0] * inv, a[1] * inv),
                   cvtpk(a[2] * inv, a[3] * inv) };
      *(u32x2*)(Ab + db * 16 + lg * 4) = st;
    }
  }
}

// ---------------- launch ----------------
extern "C" void kernel_launch(void* const* d_in, const int* in_sizes, int n_in,
                              void* d_out, int out_size, void* d_ws, size_t ws_size,
                              hipStream_t stream) {
  const float* x    = (const float*)d_in[0];
  const float* cosp = (const float*)d_in[1];
  const float* sinp = (const float*)d_in[2];
  // d_in[3] = mask (causal, computed analytically)
  const float* Wq   = (const float*)d_in[4];
  const float* Wk   = (const float*)d_in[5];
  const float* Wv   = (const float*)d_in[6];
  const float* Wo   = (const float*)d_in[7];
  const float* bo   = (const float*)d_in[8];

  char* ws = (char*)d_ws;
  u16*   xb   = (u16*)(ws + 0);          // 16 MB  (ROWS*DIM bf16)   [reused as attn out]
  u16*   wqkv = (u16*)(ws + 16777216);   // 12 MB  (NQKV*DIM bf16)
  u16*   wout = (u16*)(ws + 29360128);   // 8 MB   (DIM*DIM bf16)
  float* cs   = (float*)(ws + 37748736); // 1 MB   (T*HD fp32)
  u16*   yqkv = (u16*)(ws + 38797312);   // 24 MB  (ROWS*NQKV bf16; q-cols read by attn)
  u16*   kr   = (u16*)(ws + 63963136);   // 4 MB
  u16*   vt   = (u16*)(ws + 68157440);   // 4 MB   (total 72,351,744 B)
  u16* aout = xb;   // attn output overwrites xb (xb consumed by GEMM1 before attn)

  constexpr int CVT_TOTAL = ROWS * DIM / 4 + DIM * DIM / 4 + 512 * DIM / 4 * 2
                          + DIM * DIM / 4 + T * HD / 4;
  cvt_all_kernel<<<(CVT_TOTAL + 255) / 256, 256, 0, stream>>>(
      x, Wq, Wk, Wv, Wo, cosp, sinp, xb, wqkv, wout, cs);

  gemm_bt_kernel<true, false><<<(ROWS / 128) * (NQKV / 128), 256, 0, stream>>>(
      xb, wqkv, yqkv, nullptr, ROWS, NQKV, DIM);

  rope_k_kernel<<<ROWS * KVH * 64 / 256, 256, 0, stream>>>(yqkv, cs, kr);
  vt_kernel<<<BATCH * KVH * (T / 64), 256, 0, stream>>>(yqkv, vt);

  attn_kernel<<<BATCH * NH * 16, 256, 0, stream>>>(yqkv, cs, kr, vt, aout);

  gemm_bt_kernel<false, true><<<(ROWS / 128) * (DIM / 128), 256, 0, stream>>>(
      aout, wout, d_out, bo, ROWS, DIM, DIM);
}